// Round 17
// baseline (138.566 us; speedup 1.0000x reference)
//
#include <hip/hip_runtime.h>
#include <hip/hip_bf16.h>
#include <math.h>
#include <stdint.h>

// InfoNCE fused: sim = A @ B^T / T  (8192x8192x512, fp32 in)
// loss = mean_i( logsumexp_j sim[i,j] - sim[i,i] )
// R17: R16 (512-thread 256x128 rolled pipeline, int8 MFMA, per-lane running
// LSE) + VALU trims: running staging pointers (no per-round addr recompute)
// and base-2 LSE domain (exp2f; log2e folded into the dequant scale).

#define NB 8192
#define DDIM 512
#define SPLITS 16
#define BM 256
#define BN 128
#define CPB (NB / SPLITS)        // 512 cols per block
#define TPB (CPB / BN)           // 4 col tiles per block
#define NROUND 32                // 4 tiles x 8 k-chunks of 64

#define DELTA 0.045f
#define INV_DELTA (1.0f / DELTA)
// dequant * 1/T * log2(e): epilogue works in base-2 logsumexp domain.
#define OUT_SCALE2 (DELTA * DELTA * 10.0f * 1.4426950408889634f)
#define LN2 0.6931471805599453f

typedef unsigned char u8;
typedef __attribute__((ext_vector_type(4))) int i32x4;

// global -> LDS direct copy, 16B per lane: HW writes ldsbase + lane*16.
__device__ __forceinline__ void gl2lds16(const u8* g, const u8* l) {
  __builtin_amdgcn_global_load_lds(
      (__attribute__((address_space(1))) unsigned int*)(uintptr_t)g,
      (__attribute__((address_space(3))) unsigned int*)(unsigned int)(uintptr_t)l,
      16, 0, 0);
}

__device__ __forceinline__ unsigned pack4(float x0, float x1, float x2, float x3) {
  int q0 = min(127, max(-127, __float2int_rn(x0 * INV_DELTA)));
  int q1 = min(127, max(-127, __float2int_rn(x1 * INV_DELTA)));
  int q2 = min(127, max(-127, __float2int_rn(x2 * INV_DELTA)));
  int q3 = min(127, max(-127, __float2int_rn(x3 * INV_DELTA)));
  return (q0 & 0xFF) | ((q1 & 0xFF) << 8) | ((q2 & 0xFF) << 16) | ((q3 & 0xFF) << 24);
}

// One wave per row: quantize a & p rows to int8, diag dot in fp32; zero out.
__global__ void cvt_diag_kernel(const float* __restrict__ a, const float* __restrict__ p,
                                u8* __restrict__ aq, u8* __restrict__ pq,
                                float* __restrict__ diag, float* __restrict__ out) {
  if (blockIdx.x == 0 && threadIdx.x == 0) out[0] = 0.f;
  int row = (blockIdx.x * 256 + threadIdx.x) >> 6;
  int lane = threadIdx.x & 63;
  const float4* ar = (const float4*)(a + (size_t)row * DDIM + lane * 8);
  const float4* pr = (const float4*)(p + (size_t)row * DDIM + lane * 8);
  float4 a0 = ar[0], a1 = ar[1];
  float4 p0 = pr[0], p1 = pr[1];
  *(uint2*)(aq + (size_t)row * DDIM + lane * 8) =
      (uint2){pack4(a0.x, a0.y, a0.z, a0.w), pack4(a1.x, a1.y, a1.z, a1.w)};
  *(uint2*)(pq + (size_t)row * DDIM + lane * 8) =
      (uint2){pack4(p0.x, p0.y, p0.z, p0.w), pack4(p1.x, p1.y, p1.z, p1.w)};
  float s = a0.x * p0.x + a0.y * p0.y + a0.z * p0.z + a0.w * p0.w +
            a1.x * p1.x + a1.y * p1.y + a1.z * p1.z + a1.w * p1.w;
  for (int off = 32; off > 0; off >>= 1) s += __shfl_down(s, off);
  if (lane == 0) diag[row] = s * 10.0f;  // / T (exact fp32, not quantized)
}

__global__ __launch_bounds__(512, 4) void gemm_lse(
    const u8* __restrict__ Aq, const u8* __restrict__ Bq,
    float* __restrict__ partM, float* __restrict__ partL) {
  // Double-buffered 64B-row chunks, R9's zero-conflict swizzle:
  // 16B octet o of row R stored at o ^ ((R>>1)&3).
  __shared__ u8 sA[2][BM * 64];       // 32 KB (256 rows)
  __shared__ u8 sB[2][BN * 64];       // 16 KB (128 cols)
  __shared__ float sMm[2][BM];        // 2 KB final wc-merge scratch
  __shared__ float sMl[2][BM];        // 2 KB

  const int tid = threadIdx.x;
  const int wave = tid >> 6;          // 0..7
  const int lane = tid & 63;
  const int quad = lane >> 4;
  const int l16 = lane & 15;
  const int wr = wave >> 1, wc = wave & 1;  // 4x2 wave grid, each 64x64

  // XCD-aware remap: 512 blocks; xcd = bid&7 gets row-tiles {xcd, xcd+8, ...}.
  const int bid = blockIdx.x;
  const int xcd = bid & 7;
  const int idx = bid >> 3;                 // 0..63
  const int rowTile = (idx & 3) * 8 + xcd;  // 0..31
  const int colSplit = idx >> 2;            // 0..15
  const int row0 = rowTile * BM;
  const int col0 = colSplit * CPB;

  // Staging: A: 2 loads/wave (rows wave*32 + j*16 + rsub), B: 1 load/wave
  // (rows wave*16 + rsub). Stored octet p = lane&3, src q = p ^ ((rsub>>1)&3).
  // Running pointers advance +64 per round; tile-boundary adjust in the
  // existing (r&7)==7 branch.
  const int rsub = lane >> 2;
  const int qsrc = (lane & 3) ^ ((rsub >> 1) & 3);
  const u8* aP = Aq + (size_t)(row0 + wave * 32 + rsub) * DDIM + qsrc * 16;
  const u8* bP = Bq + (size_t)(col0 + wave * 16 + rsub) * DDIM + qsrc * 16;
  const int ldsOffA = wave * 2048;
  const int ldsOffB = wave * 1024;

  // Fragment reads: row R = wr*64 + i*16 + l16; k-octet quad at quad^((l16>>1)&3).
  const int sw = (l16 >> 1) & 3;
  const int fragA = (wr * 64 + l16) * 64 + ((quad ^ sw) * 16);
  const int fragB = (wc * 64 + l16) * 64 + ((quad ^ sw) * 16);

#define STAGE(bf)                                 \
  do {                                            \
    gl2lds16(aP, &sA[bf][ldsOffA]);               \
    gl2lds16(aP + 16 * DDIM, &sA[bf][ldsOffA + 1024]); \
    gl2lds16(bP, &sB[bf][ldsOffB]);               \
  } while (0)

  STAGE(0);   // round 0 into buf0 (pointers currently at round 0)

  i32x4 acc[4][4];
#pragma unroll
  for (int mi = 0; mi < 4; ++mi)
#pragma unroll
    for (int ni = 0; ni < 4; ++ni) acc[mi][ni] = (i32x4){0, 0, 0, 0};

  // Per-lane running LSE in BASE-2 domain: lane owns rows wr*64+mi*16+quad*4+rr.
  float rm[4][4], rl[4][4];
#pragma unroll
  for (int mi = 0; mi < 4; ++mi)
#pragma unroll
    for (int rr = 0; rr < 4; ++rr) { rm[mi][rr] = -INFINITY; rl[mi][rr] = 0.f; }

  for (int r = 0; r < NROUND; ++r) {
    const int buf = r & 1;
    __syncthreads();               // buf staged (issued one round ago);
                                   // also: all waves done reading buf^1
    if (r < NROUND - 1) {
      // advance to round r+1 source and prefetch into buf^1
      if ((r & 7) == 7) { aP -= 448; bP += BN * DDIM - 448; }
      else             { aP += 64;  bP += 64; }
      STAGE(buf ^ 1);
    }

    i32x4 bq[4];
#pragma unroll
    for (int ni = 0; ni < 4; ++ni)
      bq[ni] = *(const i32x4*)(&sB[buf][fragB + ni * 16 * 64]);
#pragma unroll
    for (int mi = 0; mi < 4; ++mi) {
      i32x4 af = *(const i32x4*)(&sA[buf][fragA + mi * 16 * 64]);
#pragma unroll
      for (int ni = 0; ni < 4; ++ni)
        acc[mi][ni] = __builtin_amdgcn_mfma_i32_16x16x64_i8(af, bq[ni], acc[mi][ni], 0, 0, 0);
    }

    if ((r & 7) == 7) {
      // Lane-local running-LSE fold in base-2 (exp2f = raw v_exp_f32).
#pragma unroll
      for (int mi = 0; mi < 4; ++mi) {
#pragma unroll
        for (int rr = 0; rr < 4; ++rr) {
          float v0 = (float)acc[mi][0][rr] * OUT_SCALE2;
          float v1 = (float)acc[mi][1][rr] * OUT_SCALE2;
          float v2 = (float)acc[mi][2][rr] * OUT_SCALE2;
          float v3 = (float)acc[mi][3][rr] * OUT_SCALE2;
          float vm = fmaxf(fmaxf(v0, v1), fmaxf(v2, v3));
          float nm = fmaxf(rm[mi][rr], vm);
          rl[mi][rr] = rl[mi][rr] * exp2f(rm[mi][rr] - nm) +
                       (exp2f(v0 - nm) + exp2f(v1 - nm) +
                        exp2f(v2 - nm) + exp2f(v3 - nm));
          rm[mi][rr] = nm;
#pragma unroll
          for (int ni = 0; ni < 4; ++ni) acc[mi][ni][rr] = 0;  // reset for next tile
        }
      }
    }
  }

  // One cross-lane merge per block (base-2): shfl over 16 l16 lanes, then
  // the two wc halves via LDS.
#pragma unroll
  for (int mi = 0; mi < 4; ++mi) {
#pragma unroll
    for (int rr = 0; rr < 4; ++rr) {
      float m = rm[mi][rr], l = rl[mi][rr];
#pragma unroll
      for (int mask = 1; mask < 16; mask <<= 1) {
        float om = __shfl_xor(m, mask);
        float ol = __shfl_xor(l, mask);
        float nm = fmaxf(m, om);
        l = l * exp2f(m - nm) + ol * exp2f(om - nm);
        m = nm;
      }
      if (l16 == 0) {
        int rowl = wr * 64 + mi * 16 + quad * 4 + rr;
        sMm[wc][rowl] = m;
        sMl[wc][rowl] = l;
      }
    }
  }
  __syncthreads();
  if (tid < BM) {
    float m0 = sMm[0][tid], m1 = sMm[1][tid];
    float l0 = sMl[0][tid], l1 = sMl[1][tid];
    float nm = fmaxf(m0, m1);
    partM[(size_t)colSplit * NB + row0 + tid] = nm;
    partL[(size_t)colSplit * NB + row0 + tid] =
        l0 * exp2f(m0 - nm) + l1 * exp2f(m1 - nm);
  }
#undef STAGE
}

// One row per thread, 32 blocks; partials are base-2 (m2, l): final
// lse_e = (m2 + log2(l)) * ln2. block-sum -> atomicAdd (out zeroed in cvt).
__global__ void reduce_kernel(const float* __restrict__ partM,
                              const float* __restrict__ partL,
                              const float* __restrict__ diag, float* __restrict__ out) {
  __shared__ float red[4];
  int r = blockIdx.x * 256 + threadIdx.x;
  float M = -INFINITY;
#pragma unroll
  for (int s = 0; s < SPLITS; ++s) M = fmaxf(M, partM[(size_t)s * NB + r]);
  float L = 0.f;
#pragma unroll
  for (int s = 0; s < SPLITS; ++s)
    L += partL[(size_t)s * NB + r] * exp2f(partM[(size_t)s * NB + r] - M);
  float v = (M + log2f(L)) * LN2 - diag[r];
  for (int off = 32; off > 0; off >>= 1) v += __shfl_down(v, off);
  if ((threadIdx.x & 63) == 0) red[threadIdx.x >> 6] = v;
  __syncthreads();
  if (threadIdx.x == 0) {
    float s = (red[0] + red[1] + red[2] + red[3]) * (1.0f / (float)NB);
    atomicAdd(out, s);
  }
}

extern "C" void kernel_launch(void* const* d_in, const int* in_sizes, int n_in,
                              void* d_out, int out_size, void* d_ws, size_t ws_size,
                              hipStream_t stream) {
  const float* anchor = (const float*)d_in[0];
  const float* positive = (const float*)d_in[1];
  float* out = (float*)d_out;

  char* ws = (char*)d_ws;
  u8* Aq = (u8*)ws;                                      // 4 MB
  u8* Bq = (u8*)(ws + (size_t)4194304);                  // 4 MB
  float* diag = (float*)(ws + (size_t)8388608);          // 32 KB
  float* partM = (float*)(ws + (size_t)8388608 + 32768);             // 512 KB
  float* partL = (float*)(ws + (size_t)8388608 + 32768 + (size_t)SPLITS * NB * 4);

  cvt_diag_kernel<<<NB / 4, 256, 0, stream>>>(anchor, positive, Aq, Bq, diag, out);
  gemm_lse<<<512, 512, 0, stream>>>(Aq, Bq, partM, partL);
  reduce_kernel<<<NB / 256, 256, 0, stream>>>(partM, partL, diag, out);
}

// Round 18
// 125.933 us; speedup vs baseline: 1.1003x; 1.1003x over previous
//
#include <hip/hip_runtime.h>
#include <hip/hip_bf16.h>
#include <math.h>
#include <stdint.h>

// InfoNCE fused: sim = A @ B^T / T  (8192x8192x512, fp32 in)
// loss = mean_i( logsumexp_j sim[i,j] - sim[i,i] )
// R18 = R16 verbatim (measured best: gemm 57.5us, total 128.9us).
// R17's "VALU trims" (running pointers, base-2 domain) measured -9.5us
// REGRESSION: the loop-carried pointer dependency defeated the compiler's
// address scheduling. Keep the compiler-friendly form.
// Structure: 512-thread 256x128 rolled single-barrier pipeline, int8 MFMA
// (mfma_i32_16x16x64_i8), zero-conflict XOR-swizzled LDS, per-lane running
// LSE in registers, separate light reduce (NO __threadfence - R13 showed
// a device-scope fence costs ~87us in cross-XCD L2 writeback).

#define NB 8192
#define DDIM 512
#define SPLITS 16
#define BM 256
#define BN 128
#define CPB (NB / SPLITS)        // 512 cols per block
#define TPB (CPB / BN)           // 4 col tiles per block
#define NROUND 32                // 4 tiles x 8 k-chunks of 64

#define DELTA 0.045f
#define INV_DELTA (1.0f / DELTA)
#define OUT_SCALE (DELTA * DELTA * 10.0f)   // dequant * 1/T

typedef unsigned char u8;
typedef __attribute__((ext_vector_type(4))) int i32x4;

// global -> LDS direct copy, 16B per lane: HW writes ldsbase + lane*16.
__device__ __forceinline__ void gl2lds16(const u8* g, const u8* l) {
  __builtin_amdgcn_global_load_lds(
      (__attribute__((address_space(1))) unsigned int*)(uintptr_t)g,
      (__attribute__((address_space(3))) unsigned int*)(unsigned int)(uintptr_t)l,
      16, 0, 0);
}

__device__ __forceinline__ unsigned pack4(float x0, float x1, float x2, float x3) {
  int q0 = min(127, max(-127, __float2int_rn(x0 * INV_DELTA)));
  int q1 = min(127, max(-127, __float2int_rn(x1 * INV_DELTA)));
  int q2 = min(127, max(-127, __float2int_rn(x2 * INV_DELTA)));
  int q3 = min(127, max(-127, __float2int_rn(x3 * INV_DELTA)));
  return (q0 & 0xFF) | ((q1 & 0xFF) << 8) | ((q2 & 0xFF) << 16) | ((q3 & 0xFF) << 24);
}

// One wave per row: quantize a & p rows to int8, diag dot in fp32; zero out.
__global__ void cvt_diag_kernel(const float* __restrict__ a, const float* __restrict__ p,
                                u8* __restrict__ aq, u8* __restrict__ pq,
                                float* __restrict__ diag, float* __restrict__ out) {
  if (blockIdx.x == 0 && threadIdx.x == 0) out[0] = 0.f;
  int row = (blockIdx.x * 256 + threadIdx.x) >> 6;
  int lane = threadIdx.x & 63;
  const float4* ar = (const float4*)(a + (size_t)row * DDIM + lane * 8);
  const float4* pr = (const float4*)(p + (size_t)row * DDIM + lane * 8);
  float4 a0 = ar[0], a1 = ar[1];
  float4 p0 = pr[0], p1 = pr[1];
  *(uint2*)(aq + (size_t)row * DDIM + lane * 8) =
      (uint2){pack4(a0.x, a0.y, a0.z, a0.w), pack4(a1.x, a1.y, a1.z, a1.w)};
  *(uint2*)(pq + (size_t)row * DDIM + lane * 8) =
      (uint2){pack4(p0.x, p0.y, p0.z, p0.w), pack4(p1.x, p1.y, p1.z, p1.w)};
  float s = a0.x * p0.x + a0.y * p0.y + a0.z * p0.z + a0.w * p0.w +
            a1.x * p1.x + a1.y * p1.y + a1.z * p1.z + a1.w * p1.w;
  for (int off = 32; off > 0; off >>= 1) s += __shfl_down(s, off);
  if (lane == 0) diag[row] = s * 10.0f;  // / T (exact fp32, not quantized)
}

__global__ __launch_bounds__(512, 4) void gemm_lse(
    const u8* __restrict__ Aq, const u8* __restrict__ Bq,
    float* __restrict__ partM, float* __restrict__ partL) {
  // Double-buffered 64B-row chunks, R9's zero-conflict swizzle:
  // 16B octet o of row R stored at o ^ ((R>>1)&3).
  __shared__ u8 sA[2][BM * 64];       // 32 KB (256 rows)
  __shared__ u8 sB[2][BN * 64];       // 16 KB (128 cols)
  __shared__ float sMm[2][BM];        // 2 KB final wc-merge scratch
  __shared__ float sMl[2][BM];        // 2 KB

  const int tid = threadIdx.x;
  const int wave = tid >> 6;          // 0..7
  const int lane = tid & 63;
  const int quad = lane >> 4;
  const int l16 = lane & 15;
  const int wr = wave >> 1, wc = wave & 1;  // 4x2 wave grid, each 64x64

  // XCD-aware remap: 512 blocks; xcd = bid&7 gets row-tiles {xcd, xcd+8, ...}.
  const int bid = blockIdx.x;
  const int xcd = bid & 7;
  const int idx = bid >> 3;                 // 0..63
  const int rowTile = (idx & 3) * 8 + xcd;  // 0..31
  const int colSplit = idx >> 2;            // 0..15
  const int row0 = rowTile * BM;
  const int col0 = colSplit * CPB;

  // Staging: A: 2 loads/wave (rows wave*32 + j*16 + rsub), B: 1 load/wave
  // (rows wave*16 + rsub). Stored octet p = lane&3, src q = p ^ ((rsub>>1)&3).
  const int rsub = lane >> 2;
  const int qsrc = (lane & 3) ^ ((rsub >> 1) & 3);
  const u8* aCol = Aq + (size_t)(row0 + wave * 32 + rsub) * DDIM + qsrc * 16;
  const u8* bCol = Bq + (size_t)(col0 + wave * 16 + rsub) * DDIM + qsrc * 16;
  const int ldsOffA = wave * 2048;
  const int ldsOffB = wave * 1024;

  // Fragment reads: row R = wr*64 + i*16 + l16; k-octet quad at quad^((l16>>1)&3).
  const int sw = (l16 >> 1) & 3;
  const int fragA = (wr * 64 + l16) * 64 + ((quad ^ sw) * 16);
  const int fragB = (wc * 64 + l16) * 64 + ((quad ^ sw) * 16);

  // Round r (0..31): tile t = r>>3, k-chunk kk = (r&7)*64, buffer r&1.
  // Address recompute per round is intentional: it is dependency-free and
  // the compiler schedules it better than a loop-carried pointer (R17).
#define STAGE(r)                                                        \
  do {                                                                  \
    int _t = (r) >> 3, _kk = ((r) & 7) << 6, _bf = (r) & 1;             \
    const u8* _a = aCol + _kk;                                          \
    const u8* _b = bCol + _t * (BN * DDIM) + _kk;                       \
    gl2lds16(_a, &sA[_bf][ldsOffA]);                                    \
    gl2lds16(_a + 16 * DDIM, &sA[_bf][ldsOffA + 1024]);                 \
    gl2lds16(_b, &sB[_bf][ldsOffB]);                                    \
  } while (0)

  STAGE(0);

  i32x4 acc[4][4];
#pragma unroll
  for (int mi = 0; mi < 4; ++mi)
#pragma unroll
    for (int ni = 0; ni < 4; ++ni) acc[mi][ni] = (i32x4){0, 0, 0, 0};

  // Per-lane running LSE: lane owns rows wr*64+mi*16+quad*4+rr, 4 cols/tile
  // (wc*64 + ni*16 + l16), accumulated across all 4 tiles lane-locally.
  float rm[4][4], rl[4][4];
#pragma unroll
  for (int mi = 0; mi < 4; ++mi)
#pragma unroll
    for (int rr = 0; rr < 4; ++rr) { rm[mi][rr] = -INFINITY; rl[mi][rr] = 0.f; }

  for (int r = 0; r < NROUND; ++r) {
    const int buf = r & 1;
    __syncthreads();               // buf staged (issued one round ago);
                                   // also: all waves done reading buf^1
    if (r < NROUND - 1) STAGE(r + 1);  // prefetch into buf^1

    i32x4 bq[4];
#pragma unroll
    for (int ni = 0; ni < 4; ++ni)
      bq[ni] = *(const i32x4*)(&sB[buf][fragB + ni * 16 * 64]);
#pragma unroll
    for (int mi = 0; mi < 4; ++mi) {
      i32x4 af = *(const i32x4*)(&sA[buf][fragA + mi * 16 * 64]);
#pragma unroll
      for (int ni = 0; ni < 4; ++ni)
        acc[mi][ni] = __builtin_amdgcn_mfma_i32_16x16x64_i8(af, bq[ni], acc[mi][ni], 0, 0, 0);
    }

    if ((r & 7) == 7) {
      // Lane-local running-LSE fold (no shfl, no LDS): 16 rows x 4 cols.
#pragma unroll
      for (int mi = 0; mi < 4; ++mi) {
#pragma unroll
        for (int rr = 0; rr < 4; ++rr) {
          float v0 = (float)acc[mi][0][rr] * OUT_SCALE;
          float v1 = (float)acc[mi][1][rr] * OUT_SCALE;
          float v2 = (float)acc[mi][2][rr] * OUT_SCALE;
          float v3 = (float)acc[mi][3][rr] * OUT_SCALE;
          float vm = fmaxf(fmaxf(v0, v1), fmaxf(v2, v3));
          float nm = fmaxf(rm[mi][rr], vm);
          rl[mi][rr] = rl[mi][rr] * __expf(rm[mi][rr] - nm) +
                       (__expf(v0 - nm) + __expf(v1 - nm) +
                        __expf(v2 - nm) + __expf(v3 - nm));
          rm[mi][rr] = nm;
#pragma unroll
          for (int ni = 0; ni < 4; ++ni) acc[mi][ni][rr] = 0;  // reset for next tile
        }
      }
    }
  }

  // One cross-lane merge per block: shfl over the 16 l16 lanes, then the
  // two wc halves via LDS.
#pragma unroll
  for (int mi = 0; mi < 4; ++mi) {
#pragma unroll
    for (int rr = 0; rr < 4; ++rr) {
      float m = rm[mi][rr], l = rl[mi][rr];
#pragma unroll
      for (int mask = 1; mask < 16; mask <<= 1) {
        float om = __shfl_xor(m, mask);
        float ol = __shfl_xor(l, mask);
        float nm = fmaxf(m, om);
        l = l * __expf(m - nm) + ol * __expf(om - nm);
        m = nm;
      }
      if (l16 == 0) {
        int rowl = wr * 64 + mi * 16 + quad * 4 + rr;
        sMm[wc][rowl] = m;
        sMl[wc][rowl] = l;
      }
    }
  }
  __syncthreads();
  if (tid < BM) {
    float m0 = sMm[0][tid], m1 = sMm[1][tid];
    float l0 = sMl[0][tid], l1 = sMl[1][tid];
    float nm = fmaxf(m0, m1);
    partM[(size_t)colSplit * NB + row0 + tid] = nm;
    partL[(size_t)colSplit * NB + row0 + tid] =
        l0 * __expf(m0 - nm) + l1 * __expf(m1 - nm);
  }
#undef STAGE
}

// One row per thread, 32 blocks; block-sum -> atomicAdd (out zeroed in cvt).
__global__ void reduce_kernel(const float* __restrict__ partM,
                              const float* __restrict__ partL,
                              const float* __restrict__ diag, float* __restrict__ out) {
  __shared__ float red[4];
  int r = blockIdx.x * 256 + threadIdx.x;
  float M = -INFINITY;
#pragma unroll
  for (int s = 0; s < SPLITS; ++s) M = fmaxf(M, partM[(size_t)s * NB + r]);
  float L = 0.f;
#pragma unroll
  for (int s = 0; s < SPLITS; ++s)
    L += partL[(size_t)s * NB + r] * __expf(partM[(size_t)s * NB + r] - M);
  float v = M + __logf(L) - diag[r];
  for (int off = 32; off > 0; off >>= 1) v += __shfl_down(v, off);
  if ((threadIdx.x & 63) == 0) red[threadIdx.x >> 6] = v;
  __syncthreads();
  if (threadIdx.x == 0) {
    float s = (red[0] + red[1] + red[2] + red[3]) * (1.0f / (float)NB);
    atomicAdd(out, s);
  }
}

extern "C" void kernel_launch(void* const* d_in, const int* in_sizes, int n_in,
                              void* d_out, int out_size, void* d_ws, size_t ws_size,
                              hipStream_t stream) {
  const float* anchor = (const float*)d_in[0];
  const float* positive = (const float*)d_in[1];
  float* out = (float*)d_out;

  char* ws = (char*)d_ws;
  u8* Aq = (u8*)ws;                                      // 4 MB
  u8* Bq = (u8*)(ws + (size_t)4194304);                  // 4 MB
  float* diag = (float*)(ws + (size_t)8388608);          // 32 KB
  float* partM = (float*)(ws + (size_t)8388608 + 32768);             // 512 KB
  float* partL = (float*)(ws + (size_t)8388608 + 32768 + (size_t)SPLITS * NB * 4);

  cvt_diag_kernel<<<NB / 4, 256, 0, stream>>>(anchor, positive, Aq, Bq, diag, out);
  gemm_lse<<<512, 512, 0, stream>>>(Aq, Bq, partM, partL);
  reduce_kernel<<<NB / 256, 256, 0, stream>>>(partM, partL, diag, out);
}